// Round 7
// baseline (21041.940 us; speedup 1.0000x reference)
//
#include <hip/hip_runtime.h>
#include <math.h>

#define NB 256
#define NN 256
#define NK 128
#define ND 256
#define NH 512
#define NT 1024
#define LDA 520

// output layout (floats): x | f_out | u | p_u
#define OUT_X 0
#define OUT_F 65536
#define OUT_U 131072
#define OUT_P 196608

// per-batch ws layout (float offsets)
#define EPB   65280              // E slabs levels 1..8 (255*256)
#define SP4O  (EPB)              // spec d4: 8*2*256
#define SP5O  (SP4O + 4096)      // 4*2*256
#define SP6O  (SP5O + 2048)      // 2*2*256
#define S1O   (SP6O + 1024)      // 2*256
#define S2O   (S1O + 512)        // 4*256
#define S3O   (S2O + 1024)       // 8*256
#define LOFFI (S3O + 2048)       // 256 ints (decision-bit slabs)
#define DUMPO (LOFFI + 256)      // 256-float dump row for padded GEMM rows
#define BPB   (DUMPO + 256)

__host__ __device__ __forceinline__ int loff(int d) { return 256 - (1 << (9 - d)); }

struct SMem {
  float A[16 * LDA];     // 8320 f  — staged GEMM1 inputs
  float part[8192];      // k-split partial sums
  float hid[24 * 512];   // 12288 f — hidden rows
  float emb[2 * 512];    // label_emb[bit] @ bnW1[512:768]
  float* rowDst[32];     // per-row output pointers (slot 0..15 cn, 16..31 bn)
  int cur[256], nxt[256];
  float red[8];
  int qb[4];
  int bitR[16];
  int fmap[256];
};

// ---------- GEMM1 plain: 16 rows x 512 cols, K=512 ----------
// layout: rh(2) x kh(2) x colpair(256); acc[8][2]; weight double-buffer.
template <int MODE>  // 0 = cn, 1 = bn (+emb[bitR])
__device__ void g1_plain(SMem* sm, int tid, const float* __restrict__ W1,
                         const float* __restrict__ b1) {
  const int rh = tid >> 9;
  const int kh = (tid >> 8) & 1;
  const int cp = tid & 255;
  const int c0 = cp * 2;
  const int r0 = rh * 8;
  const int k0 = kh * 256;
  float acc[8][2];
#pragma unroll
  for (int r = 0; r < 8; ++r) { acc[r][0] = 0.f; acc[r][1] = 0.f; }
  const float* Wp = W1 + (size_t)k0 * NH + c0;
  float2 wn[4];
#pragma unroll
  for (int j = 0; j < 4; ++j) wn[j] = *(const float2*)(Wp + (size_t)j * NH);
  for (int kc = 0; kc < 256; kc += 4) {
    float2 w[4];
#pragma unroll
    for (int j = 0; j < 4; ++j) w[j] = wn[j];
    if (kc + 4 < 256) {
      const float* Wq = Wp + (size_t)(kc + 4) * NH;
#pragma unroll
      for (int j = 0; j < 4; ++j) wn[j] = *(const float2*)(Wq + (size_t)j * NH);
    }
    const float* Ab = &sm->A[r0 * LDA + k0 + kc];
#pragma unroll
    for (int r = 0; r < 8; ++r) {
      const float4 a = *(const float4*)(Ab + r * LDA);
      acc[r][0] += a.x * w[0].x + a.y * w[1].x + a.z * w[2].x + a.w * w[3].x;
      acc[r][1] += a.x * w[0].y + a.y * w[1].y + a.z * w[2].y + a.w * w[3].y;
    }
  }
  if (kh == 1) {
#pragma unroll
    for (int r = 0; r < 8; ++r)
      *(float2*)&sm->part[(r0 + r) * 512 + c0] = make_float2(acc[r][0], acc[r][1]);
  }
  __syncthreads();
  if (kh == 0) {
#pragma unroll
    for (int r = 0; r < 8; ++r) {
      const int rr = r0 + r;
#pragma unroll
      for (int n = 0; n < 2; ++n) {
        const int c = c0 + n;
        float s = acc[r][n] + sm->part[rr * 512 + c] + b1[c];
        if (MODE == 1) s += sm->emb[sm->bitR[rr] * 512 + c];
        sm->hid[rr * 512 + c] = fmaxf(s, 0.f);
      }
    }
  }
  __syncthreads();
}

// ---------- GEMM1 fused: R rows x 1024 cols (cn | bn-base), K=512 ----------
// layout: kh(2) x colpair(512); acc[R][2]; bn cols -> 2 ReLU variants.
template <int R>
__device__ void g1_fused(SMem* sm, int tid, const float* __restrict__ Wcn,
                         const float* __restrict__ Wbn,
                         const float* __restrict__ bcn,
                         const float* __restrict__ bbn) {
  const int kh = tid >> 9;
  const int cp = tid & 511;
  const int c0 = cp * 2;
  const int k0 = kh * 256;
  const float* Wp = ((c0 < 512) ? (Wcn + c0) : (Wbn + (c0 - 512))) + (size_t)k0 * NH;
  float acc[R][2];
#pragma unroll
  for (int r = 0; r < R; ++r) { acc[r][0] = 0.f; acc[r][1] = 0.f; }
  float2 wn[4];
#pragma unroll
  for (int j = 0; j < 4; ++j) wn[j] = *(const float2*)(Wp + (size_t)j * NH);
  for (int kc = 0; kc < 256; kc += 4) {
    float2 w[4];
#pragma unroll
    for (int j = 0; j < 4; ++j) w[j] = wn[j];
    if (kc + 4 < 256) {
      const float* Wq = Wp + (size_t)(kc + 4) * NH;
#pragma unroll
      for (int j = 0; j < 4; ++j) wn[j] = *(const float2*)(Wq + (size_t)j * NH);
    }
    const float* Ab = &sm->A[k0 + kc];
#pragma unroll
    for (int r = 0; r < R; ++r) {
      const float4 a = *(const float4*)(Ab + r * LDA);
      acc[r][0] += a.x * w[0].x + a.y * w[1].x + a.z * w[2].x + a.w * w[3].x;
      acc[r][1] += a.x * w[0].y + a.y * w[1].y + a.z * w[2].y + a.w * w[3].y;
    }
  }
  if (kh == 1) {
#pragma unroll
    for (int r = 0; r < R; ++r)
      *(float2*)&sm->part[r * 1024 + c0] = make_float2(acc[r][0], acc[r][1]);
  }
  __syncthreads();
  if (kh == 0) {
#pragma unroll
    for (int r = 0; r < R; ++r) {
#pragma unroll
      for (int n = 0; n < 2; ++n) {
        const int c = c0 + n;
        const float pre = acc[r][n] + sm->part[r * 1024 + c];
        if (c < 512) {
          sm->hid[r * 512 + c] = fmaxf(pre + bcn[c], 0.f);
        } else {
          const int cb = c - 512;
          const float base = pre + bbn[cb];
          sm->hid[(R + 2 * r) * 512 + cb] = fmaxf(base + sm->emb[cb], 0.f);
          sm->hid[(R + 2 * r + 1) * 512 + cb] = fmaxf(base + sm->emb[512 + cb], 0.f);
        }
      }
    }
  }
  __syncthreads();
}

// ---------- GEMM2: RTP rows (from hid[hidBase..]) x 256 cols, K=512 ----------
// layout: rq(4) x kh(2) x colpair(128); acc[RTP/4][2]; single weight matrix.
template <int RTP>
__device__ void g2(SMem* sm, int tid, int hidBase, int slot,
                   const float* __restrict__ W2, const float* __restrict__ b2) {
  constexpr int RQ = RTP / 4;
  const int rq = tid >> 8;
  const int kh = (tid >> 7) & 1;
  const int cp = tid & 127;
  const int c0 = cp * 2;
  const int k0 = kh * 256;
  const int lr0 = rq * RQ;
  const int r0 = hidBase + lr0;
  float acc[RQ][2];
#pragma unroll
  for (int r = 0; r < RQ; ++r) { acc[r][0] = 0.f; acc[r][1] = 0.f; }
  const float* Wp = W2 + (size_t)k0 * ND + c0;
  float2 wn[4];
#pragma unroll
  for (int j = 0; j < 4; ++j) wn[j] = *(const float2*)(Wp + (size_t)j * ND);
  for (int kc = 0; kc < 256; kc += 4) {
    float2 w[4];
#pragma unroll
    for (int j = 0; j < 4; ++j) w[j] = wn[j];
    if (kc + 4 < 256) {
      const float* Wq = Wp + (size_t)(kc + 4) * ND;
#pragma unroll
      for (int j = 0; j < 4; ++j) wn[j] = *(const float2*)(Wq + (size_t)j * ND);
    }
    const float* Hb = &sm->hid[r0 * 512 + k0 + kc];
#pragma unroll
    for (int r = 0; r < RQ; ++r) {
      const float4 a = *(const float4*)(Hb + r * 512);
      acc[r][0] += a.x * w[0].x + a.y * w[1].x + a.z * w[2].x + a.w * w[3].x;
      acc[r][1] += a.x * w[0].y + a.y * w[1].y + a.z * w[2].y + a.w * w[3].y;
    }
  }
  if (kh == 1) {
#pragma unroll
    for (int r = 0; r < RQ; ++r)
      *(float2*)&sm->part[(lr0 + r) * 256 + c0] = make_float2(acc[r][0], acc[r][1]);
  }
  __syncthreads();
  if (kh == 0) {
#pragma unroll
    for (int r = 0; r < RQ; ++r) {
#pragma unroll
      for (int n = 0; n < 2; ++n) {
        const int c = c0 + n;
        const float s = acc[r][n] + sm->part[(lr0 + r) * 256 + c] + b2[c];
        sm->rowDst[slot + lr0 + r][c] = s;
      }
    }
  }
  __syncthreads();
}

// ---------- A staging ----------
__device__ __forceinline__ void stageA(SMem* sm, int tid, const float* __restrict__ Ed,
                                       const float* __restrict__ obs2, int p0, int R) {
  for (int i = tid; i < R * 128; i += NT) {
    const int r = i >> 7, q = i & 127, k = q * 4;
    float4 v;
    if (Ed == nullptr) v = *(const float4*)&obs2[k & 255];
    else v = *(const float4*)&Ed[(size_t)(2 * (p0 + r) + (k >> 8)) * ND + (k & 255)];
    *(float4*)&sm->A[r * LDA + k] = v;
  }
}

__device__ __forceinline__ void stageA_d7(SMem* sm, int tid, const float* __restrict__ E,
                                          const float* __restrict__ sp6) {
  for (int i = tid; i < 5 * 128; i += NT) {
    const int r = i >> 7, q = i & 127, k = q * 4;
    const int h = k >> 8;
    const float* src;
    if (r == 0) src = E + (size_t)(252 + h) * ND;
    else {
      const int cc = r - 1;
      const int bit = (h == 0) ? (cc >> 1) : (cc & 1);
      src = sp6 + (size_t)(h * 2 + bit) * ND;
    }
    *(float4*)&sm->A[r * LDA + k] = *(const float4*)&src[k & 255];
  }
}

__global__ __launch_bounds__(NT, 4) void sc_spec(
    const int* __restrict__ info_bits, const float* __restrict__ rv,
    const int* __restrict__ info_set,
    const float* __restrict__ obs_emb, const float* __restrict__ label_emb,
    const float* __restrict__ cnW1, const float* __restrict__ cnb1,
    const float* __restrict__ cnW2, const float* __restrict__ cnb2,
    const float* __restrict__ bnW1, const float* __restrict__ bnb1,
    const float* __restrict__ bnW2, const float* __restrict__ bnb2,
    const float* __restrict__ llrW, const float* __restrict__ llrb,
    float* __restrict__ out, float* __restrict__ ws) {
  __shared__ SMem sm;
  const int tid = threadIdx.x, b = blockIdx.x;
  float* wsb = ws + (size_t)b * BPB;
  float* E = wsb;
  float* sp4 = wsb + SP4O;
  float* sp5 = wsb + SP5O;
  float* sp6 = wsb + SP6O;
  float* S1 = wsb + S1O;
  float* S2 = wsb + S2O;
  float* S3 = wsb + S3O;
  float* dump = wsb + DUMPO;
  int* Lb = (int*)(wsb + LOFFI);
  const float* obs2 = obs_emb + 2 * ND;

  // ---- init: embC + fmap ----
  {
    const int bit = tid >> 9, col = tid & 511;
    float s = 0.f;
#pragma unroll 4
    for (int j = 0; j < ND; ++j)
      s += label_emb[bit * ND + j] * bnW1[(size_t)(NH + j) * NH + col];
    sm.emb[bit * 512 + col] = s;
  }
  if (tid < 256) sm.fmap[tid] = -1;
  __syncthreads();
  if (tid < NK) sm.fmap[info_set[tid]] = tid;
  __syncthreads();

  auto plainPass = [&](int d, bool isBn, int p0) {
    const float* Ed = (d == 0) ? nullptr : E + (size_t)loff(d) * ND;
    float* dstE = E + (size_t)loff(d + 1) * ND;
    stageA(&sm, tid, Ed, obs2, p0, 16);
    if (isBn && tid < 16) sm.bitR[tid] = Lb[loff(d + 1) + p0 + tid];
    if (tid < 16) sm.rowDst[tid] = dstE + (size_t)(p0 + tid) * ND;
    __syncthreads();
    if (!isBn) {
      g1_plain<0>(&sm, tid, cnW1, cnb1);
      g2<16>(&sm, tid, 0, 0, cnW2, cnb2);
    } else {
      g1_plain<1>(&sm, tid, bnW1, bnb1);
      g2<16>(&sm, tid, 0, 0, bnW2, bnb2);
    }
  };

  auto fusedPass = [&](int d) {
    const int P = 1 << (7 - d);  // 8,4,2
    const float* Ed = E + (size_t)loff(d) * ND;
    float* dstE = E + (size_t)loff(d + 1) * ND;
    float* spd = (d == 4) ? sp4 : (d == 5) ? sp5 : sp6;
    stageA(&sm, tid, Ed, obs2, 0, P);
    if (tid < 32) {
      float* dst = dump;
      if (tid < P) dst = dstE + (size_t)tid * ND;
      else if (tid >= 16 && tid < 16 + 2 * P) dst = spd + (size_t)(tid - 16) * ND;
      sm.rowDst[tid] = dst;
    }
    __syncthreads();
    if (d == 4) {
      g1_fused<8>(&sm, tid, cnW1, bnW1, cnb1, bnb1);
      g2<8>(&sm, tid, 0, 0, cnW2, cnb2);
      g2<16>(&sm, tid, 8, 16, bnW2, bnb2);
    } else if (d == 5) {
      g1_fused<4>(&sm, tid, cnW1, bnW1, cnb1, bnb1);
      g2<4>(&sm, tid, 0, 0, cnW2, cnb2);
      g2<8>(&sm, tid, 4, 16, bnW2, bnb2);
    } else {
      g1_fused<2>(&sm, tid, cnW1, bnW1, cnb1, bnb1);
      g2<4>(&sm, tid, 0, 0, cnW2, cnb2);   // rows 2,3 -> dump
      g2<4>(&sm, tid, 2, 16, bnW2, bnb2);
    }
  };

  auto d7comb = [&]() {
    stageA_d7(&sm, tid, E, sp6);
    if (tid < 32) {
      float* dst = dump;
      if (tid == 0) dst = E + (size_t)254 * ND;
      else if (tid >= 1 && tid <= 4) dst = S2 + (size_t)(tid - 1) * ND;
      else if (tid >= 16 && tid <= 17) dst = S1 + (size_t)(tid - 16) * ND;
      else if (tid >= 18 && tid <= 25) dst = S3 + (size_t)(tid - 18) * ND;
      sm.rowDst[tid] = dst;
    }
    __syncthreads();
    g1_fused<5>(&sm, tid, cnW1, bnW1, cnb1, bnb1);
    g2<8>(&sm, tid, 0, 0, cnW2, cnb2);    // rows 5-7 -> dump
    g2<12>(&sm, tid, 5, 16, bnW2, bnb2);  // rows 15,16 -> dump
  };

  auto selectSpec = [&](int d) {  // d in {4,5}
    const int P = 1 << (7 - d);
    const float* spd = (d == 4) ? sp4 : sp5;
    float* dstE = E + (size_t)loff(d + 1) * ND;
    for (int i = tid; i < P * ND; i += NT) {
      const int p = i >> 8, c = i & 255;
      const int bit = Lb[loff(d + 1) + p];
      dstE[p * ND + c] = spd[(size_t)(p * 2 + bit) * ND + c];
    }
    __syncthreads();
  };

  auto leaf = [&](int off, const float* src) {
    if (tid < 256) {
      const float ev = src[tid];
      float v0 = ev * llrW[2 * tid];
      float v1 = ev * llrW[2 * tid + 1];
#pragma unroll
      for (int o = 32; o > 0; o >>= 1) {
        v0 += __shfl_down(v0, o);
        v1 += __shfl_down(v1, o);
      }
      if ((tid & 63) == 0) {
        sm.red[tid >> 6] = v0;
        sm.red[4 + (tid >> 6)] = v1;
      }
    }
    __syncthreads();
    if (tid == 0) {
      const float l0 = sm.red[0] + sm.red[1] + sm.red[2] + sm.red[3] + llrb[0];
      const float l1 = sm.red[4] + sm.red[5] + sm.red[6] + sm.red[7] + llrb[1];
      const float m = fmaxf(l0, l1);
      const float e0 = expf(l0 - m), e1 = expf(l1 - m);
      const float s = e0 + e1;
      const float p0 = e0 / s, p1 = e1 / s;
      const int hard = (rv[b * NN + off] > p0) ? 1 : 0;
      const int fidx = sm.fmap[off];
      const int fval = (fidx >= 0) ? info_bits[b * NK + fidx] : 2;
      const int xb = (fval == 2) ? hard : fval;
      out[OUT_F + b * NN + off] = (fidx >= 0) ? 2.0f : (float)xb;
      out[OUT_U + b * NN + off] = (float)xb;
      out[OUT_P + (b * NN + off) * 2 + 0] = p0;
      out[OUT_P + (b * NN + off) * 2 + 1] = p1;
      sm.cur[0] = xb;
      sm.qb[off & 3] = xb;
    }
    __syncthreads();
    int* cur = sm.cur;
    int* nxt = sm.nxt;
    int len = 1, lev = 8, idx = off;
    while (idx & 1) {
      if (tid < len) {
        const int c = cur[tid];
        nxt[2 * tid] = Lb[loff(lev) + tid] ^ c;
        nxt[2 * tid + 1] = c;
      }
      __syncthreads();
      int* t = cur; cur = nxt; nxt = t;
      len <<= 1; idx >>= 1; --lev;
    }
    if (lev > 0) {
      if (tid < len) Lb[loff(lev) + tid] = cur[tid];
    } else {
      if (tid < 256) out[OUT_X + b * NN + tid] = (float)cur[tid];
    }
    __syncthreads();
  };

  // ---- initial descent ----
  for (int d = 0; d < 4; ++d)
    for (int p0 = 0; p0 < (1 << (7 - d)); p0 += 16) plainPass(d, false, p0);
  fusedPass(4); fusedPass(5); fusedPass(6);
  d7comb();

  // ---- leaf loop ----
  for (int off = 0; off < NN; ++off) {
    const int ph = off & 3;
    const float* src;
    if (ph == 0) src = E + (size_t)254 * ND;
    else if (ph == 1) src = S1 + (size_t)sm.qb[0] * ND;
    else {
      const int cidx = 2 * (sm.qb[0] ^ sm.qb[1]) + sm.qb[1];
      src = (ph == 2) ? (S2 + (size_t)cidx * ND) : (S3 + (size_t)(2 * cidx + sm.qb[2]) * ND);
    }
    leaf(off, src);
    if (off == NN - 1) break;
    const int t = off + 1;
    const int z = __ffs(t) - 1;
    if (z <= 1) continue;  // inside a size-4 quad: everything speculated
    const int dbn = 7 - z;  // <= 5
    if (dbn >= 4) {
      selectSpec(dbn);
    } else {
      for (int p0 = 0; p0 < (1 << (7 - dbn)); p0 += 16) plainPass(dbn, true, p0);
    }
    for (int d = dbn + 1; d < 4; ++d)
      for (int p0 = 0; p0 < (1 << (7 - d)); p0 += 16) plainPass(d, false, p0);
    for (int d = (dbn + 1 > 4 ? dbn + 1 : 4); d < 7; ++d) fusedPass(d);
    d7comb();
  }
}

extern "C" void kernel_launch(void* const* d_in, const int* in_sizes, int n_in,
                              void* d_out, int out_size, void* d_ws, size_t ws_size,
                              hipStream_t stream) {
  const int*   info_bits = (const int*)d_in[0];
  const float* rv        = (const float*)d_in[1];
  const int*   info_set  = (const int*)d_in[2];
  const float* obs_emb   = (const float*)d_in[3];
  const float* label_emb = (const float*)d_in[4];
  const float* cnW1      = (const float*)d_in[5];
  const float* cnb1      = (const float*)d_in[6];
  const float* cnW2      = (const float*)d_in[7];
  const float* cnb2      = (const float*)d_in[8];
  const float* bnW1      = (const float*)d_in[9];
  const float* bnb1      = (const float*)d_in[10];
  const float* bnW2      = (const float*)d_in[11];
  const float* bnb2      = (const float*)d_in[12];
  const float* llrW      = (const float*)d_in[13];
  const float* llrb      = (const float*)d_in[14];

  float* out = (float*)d_out;
  float* ws  = (float*)d_ws;

  sc_spec<<<dim3(NB), dim3(NT), 0, stream>>>(
      info_bits, rv, info_set, obs_emb, label_emb,
      cnW1, cnb1, cnW2, cnb2, bnW1, bnb1, bnW2, bnb2,
      llrW, llrb, out, ws);
}